// Round 6
// baseline (352.859 us; speedup 1.0000x reference)
//
#include <hip/hip_runtime.h>
#include <hip/hip_bf16.h>

#define Bb 2
#define Ss 4096
#define Dd 512
#define Hh 8
#define DHh 64

typedef __attribute__((ext_vector_type(8))) short short8;
typedef __attribute__((ext_vector_type(4))) float floatx4;

static __device__ __forceinline__ ushort bfbits(float f) {
  union { __hip_bfloat16 h; ushort u; } cv;
  cv.h = __float2bfloat16(f);
  return cv.u;
}

// pack two fp32 -> two bf16 (truncation; P-weights only, 2^-8 rel err)
static __device__ __forceinline__ unsigned int packhi(float a, float b) {
  union { float f; unsigned int u; } ca, cb; ca.f = a; cb.f = b;
  return (ca.u >> 16) | (cb.u & 0xffff0000u);
}

// ---------------- merged fp32 -> bf16: [x | Wq | Wk | Wv | Wo] ----------------
__global__ void cvt_all(const float* __restrict__ x,
                        const float* __restrict__ w0, const float* __restrict__ w1,
                        const float* __restrict__ w2, const float* __restrict__ w3,
                        ushort* __restrict__ out) {
  const int XN4 = (Bb * Ss * Dd) / 4;
  const int WN4 = (Dd * Dd) / 4;        // 65,536 = 2^16
  int i = blockIdx.x * blockDim.x + threadIdx.x;
  if (i >= XN4 + 4 * WN4) return;
  const float* s; int li;
  if (i < XN4) { s = x; li = i; }
  else {
    int t = i - XN4; int j = t >> 16; li = t & (WN4 - 1);
    s = (j == 0) ? w0 : (j == 1) ? w1 : (j == 2) ? w2 : w3;
  }
  float4 f = ((const float4*)s)[li];
  ushort4 u;
  u.x = bfbits(f.x); u.y = bfbits(f.y); u.z = bfbits(f.z); u.w = bfbits(f.w);
  ((ushort4*)out)[i] = u;
}

// permuted V^T position: key s -> within-64 slot so flash PV A-frags are
// single contiguous 16B loads.
static __device__ __forceinline__ int vperm(int s0) {  // s0 multiple of 4
  int kb = (s0 >> 4) & 3, gq = (s0 >> 2) & 3;
  return (s0 & ~63) | ((kb >> 1) << 5) | (gq << 3) | ((kb & 1) << 2);
}

// ---------------- fused QKV projection GEMM ----------------
// Wave computes 64x64 (4x4 MFMA tiles): 8 loads per 16 MFMAs per K-step-32.
// Block = 4 waves (2x2) = 128x128 tile. Grid 64 mb x 12 (which x nb) = 768.
#define LDQK(buf, k0)                                                          \
  _Pragma("unroll")                                                            \
  for (int rb = 0; rb < 4; ++rb)                                               \
    af[buf][rb] = *(const short8*)(ap + (size_t)rb * 16 * 512 + (k0));         \
  _Pragma("unroll")                                                            \
  for (int cb = 0; cb < 4; ++cb)                                               \
    bf[buf][cb] = *(const short8*)(bp + (size_t)cb * 16 * 512 + (k0));

__global__ __launch_bounds__(256) void qkv_gemm(
    const ushort* __restrict__ xb,
    const ushort* __restrict__ Wq, const ushort* __restrict__ Wk, const ushort* __restrict__ Wv,
    const float* __restrict__ bq, const float* __restrict__ bk, const float* __restrict__ bv,
    ushort* __restrict__ qo, ushort* __restrict__ ko, ushort* __restrict__ vo)
{
  int mb = blockIdx.x / 12, rest = blockIdx.x % 12;
  int which = rest >> 2, nb = rest & 3;
  const ushort* Bw  = (which == 0) ? Wq : (which == 1) ? Wk : Wv;
  const float* bias = (which == 0) ? bq : (which == 1) ? bk : bv;
  int lane = threadIdx.x & 63, w = threadIdx.x >> 6;
  int wr = w & 1, wc = w >> 1;
  int g = lane >> 4, ln = lane & 15;
  int m0 = mb * 128 + wr * 64;
  int c0 = nb * 128 + wc * 64;
  const ushort* ap = xb + (size_t)(m0 + ln) * 512 + g * 8;
  const ushort* bp = Bw + (size_t)(c0 + ln) * 512 + g * 8;
  floatx4 acc[4][4] = {};
  short8 af[2][4], bf[2][4];
  LDQK(0, 0)
#pragma unroll
  for (int it = 0; it < 16; ++it) {
    int cur = it & 1;
    if (it < 15) { LDQK(cur ^ 1, (it + 1) * 32) }
#pragma unroll
    for (int rb = 0; rb < 4; ++rb)
#pragma unroll
      for (int cb = 0; cb < 4; ++cb)
        acc[rb][cb] = __builtin_amdgcn_mfma_f32_16x16x32_bf16(af[cur][rb], bf[cur][cb], acc[rb][cb], 0, 0, 0);
  }
  // Q scale = (1/8) * log2(e): softmax then uses raw exp2 (v_exp_f32),
  // saving one v_mul per score element in the flash kernel.
  float scale = (which == 0) ? 0.18033688011112042f : 1.0f;
#pragma unroll
  for (int rb = 0; rb < 4; ++rb)
#pragma unroll
    for (int cb = 0; cb < 4; ++cb) {
      int col = c0 + cb * 16 + ln;
      float bv_ = bias[col];
      int hh = col >> 6, dh = col & 63;
      if (which == 2) {
        int i0 = m0 + rb * 16 + g * 4;
        int bI = i0 >> 12, s0 = i0 & (Ss - 1);
        ushort4 pk;
        pk.x = bfbits(acc[rb][cb][0] + bv_);
        pk.y = bfbits(acc[rb][cb][1] + bv_);
        pk.z = bfbits(acc[rb][cb][2] + bv_);
        pk.w = bfbits(acc[rb][cb][3] + bv_);
        *(ushort4*)(vo + (((size_t)bI * Hh + hh) * DHh + dh) * Ss + vperm(s0)) = pk;
      } else {
        ushort* outp = (which == 0) ? qo : ko;
#pragma unroll
        for (int r = 0; r < 4; ++r) {
          int i = m0 + rb * 16 + g * 4 + r;
          int bI = i >> 12, s = i & (Ss - 1);
          outp[(((size_t)bI * Hh + hh) * Ss + s) * DHh + dh] = bfbits((acc[rb][cb][r] + bv_) * scale);
        }
      }
    }
}

// ---------------- output projection GEMM (fp32 out) ----------------
#define LD32(buf, k0)                                                          \
  af[buf][0] = *(const short8*)(ap + (k0));                                    \
  af[buf][1] = *(const short8*)(ap + 16 * 512 + (k0));                         \
  _Pragma("unroll")                                                            \
  for (int ns = 0; ns < 4; ++ns)                                               \
    bfr[buf][ns] = *(const short8*)(bp + (size_t)ns * 16 * 512 + (k0));

__global__ __launch_bounds__(256) void gemm_out(
    const ushort* __restrict__ A, const ushort* __restrict__ Bw,
    const float* __restrict__ bias, float* __restrict__ outp)
{
  int mb = blockIdx.x >> 3, nb = blockIdx.x & 7;
  int lane = threadIdx.x & 63, w = threadIdx.x >> 6;
  int g = lane >> 4, ln = lane & 15;
  int m0 = mb * 128 + w * 32;
  const ushort* ap = A + (size_t)(m0 + ln) * 512 + g * 8;
  const ushort* bp = Bw + (size_t)(nb * 64 + ln) * 512 + g * 8;
  floatx4 acc[2][4] = {};
  short8 af[2][2], bfr[2][4];
  LD32(0, 0)
#pragma unroll
  for (int it = 0; it < 16; ++it) {
    int cur = it & 1;
    if (it < 15) { LD32(cur ^ 1, (it + 1) * 32) }
#pragma unroll
    for (int ns = 0; ns < 4; ++ns) {
      acc[0][ns] = __builtin_amdgcn_mfma_f32_16x16x32_bf16(af[cur][0], bfr[cur][ns], acc[0][ns], 0, 0, 0);
      acc[1][ns] = __builtin_amdgcn_mfma_f32_16x16x32_bf16(af[cur][1], bfr[cur][ns], acc[1][ns], 0, 0, 0);
    }
  }
#pragma unroll
  for (int rb = 0; rb < 2; ++rb)
#pragma unroll
    for (int ns = 0; ns < 4; ++ns) {
      int col = nb * 64 + ns * 16 + ln;
      float bv_ = bias[col];
#pragma unroll
      for (int r = 0; r < 4; ++r)
        outp[(size_t)(m0 + rb * 16 + g * 4 + r) * 512 + col] = acc[rb][ns][r] + bv_;
    }
}

// ---------------- flash attention v11 ----------------
// Register-residency experiment. v6/v8/v9/v10 all pinned at 17-22% occupancy
// (= 2 waves/SIMD) across wildly different grids/LDS -> the cap is TOTAL
// registers (arch + MFMA acc, unified file): ~104-128 arch + ~64 acc > 170
// -> floor(512/total) = 2. v11 forces 3 waves/SIMD: __launch_bounds__(256,3)
// caps total at ~170 (a few regs below current, unlike v7's impossible 128).
// Structure: de-rep'd v6 -- block (256 thr) = (bh, u); 4 waves = 2 qsel x
// 2 K-halves; grid 1024 (4 blocks/CU supplied, 3 resident); LPT dispatch
// (u = 63 - (z>>4): longest blocks first) so backfill packing hides the
// non-uniform block durations. Cheap v6-style LDS merge (no atomics).
__global__ __launch_bounds__(256, 3) void flash11(
    const ushort* __restrict__ q, const ushort* __restrict__ k,
    const ushort* __restrict__ vt, const float* __restrict__ gamma,
    ushort* __restrict__ o)
{
  __shared__ __align__(16) float Pmrg[2][64][34];   // partial O (32) + l (2)
  __shared__ __align__(16) ushort Tb[2][16 * 72];   // per-qsel transpose

  int z = blockIdx.x;
  int bh = z & 15;                 // XCD x serves bh {x, x+8}: K/V L2-resident
  int b = bh >> 3, hh = bh & 7;
  int u = 63 - (z >> 4);           // LPT: u=63 blocks dispatched first

  int tid = threadIdx.x;
  int wv = tid >> 6, lane = tid & 63;
  int qsel = wv >> 1, half = wv & 1;
  int g = lane >> 4, ln = lane & 15;

  const ushort* kp = k + ((size_t)bh * Ss + ln) * DHh + g * 8;
  const ushort* vp = vt + ((size_t)bh * DHh + ln) * Ss + g * 8;

  int t = 2 * u + qsel;
  int q0 = t * 32;
  int ktm = u;                 // diagonal (masked) tile
  int nkt = u + 1;
  int h = nkt >> 1;            // half0 (merger/storer) gets the floor half
  int lo = half ? h : 0, hi = half ? nkt : h;

  const ushort* qp = q + ((size_t)bh * Ss + q0 + ln) * DHh + g * 8;
  short8 qf00 = *(const short8*)qp;
  short8 qf01 = *(const short8*)(qp + 32);
  short8 qf10 = *(const short8*)(qp + 16 * DHh);
  short8 qf11 = *(const short8*)(qp + 16 * DHh + 32);

  int qrow0 = q0 + ln, qrow1 = q0 + 16 + ln;
  float gm0 = gamma[(size_t)b * Ss + qrow0];
  float gm1 = gamma[(size_t)b * Ss + qrow1];
  float l2[2] = {0.0f, 0.0f};
  floatx4 oacc[2][4] = {};

  short8 kfl[4], kfh[4], vf[8];
  int kb0 = lo * 64;
#pragma unroll
  for (int ns = 0; ns < 4; ++ns) {
    kfl[ns] = *(const short8*)(kp + (size_t)(kb0 + ns * 16) * DHh);
    kfh[ns] = *(const short8*)(kp + (size_t)(kb0 + ns * 16) * DHh + 32);
  }
#pragma unroll
  for (int cc = 0; cc < 8; ++cc)
    vf[cc] = *(const short8*)(vp + (size_t)((cc & 3) * 16) * Ss + kb0 + (cc >> 2) * 32);

  for (int kt = lo; kt < hi; ++kt) {
    int kbase = kt * 64;
    // ---- S^T = K . Q^T : 16 MFMAs ----
    float sv[2][16];
#pragma unroll
    for (int ns = 0; ns < 4; ++ns) {
      floatx4 z0 = {}, z1 = {};
      z0 = __builtin_amdgcn_mfma_f32_16x16x32_bf16(kfl[ns], qf00, z0, 0, 0, 0);
      z0 = __builtin_amdgcn_mfma_f32_16x16x32_bf16(kfh[ns], qf01, z0, 0, 0, 0);
      z1 = __builtin_amdgcn_mfma_f32_16x16x32_bf16(kfl[ns], qf10, z1, 0, 0, 0);
      z1 = __builtin_amdgcn_mfma_f32_16x16x32_bf16(kfh[ns], qf11, z1, 0, 0, 0);
#pragma unroll
      for (int r = 0; r < 4; ++r) { sv[0][ns * 4 + r] = z0[r]; sv[1][ns * 4 + r] = z1[r]; }
    }
    // ---- prefetch next K tile ----
    if (kt + 1 < hi) {
      const ushort* kn = kp + (size_t)(kbase + 64) * DHh;
#pragma unroll
      for (int ns = 0; ns < 4; ++ns) {
        kfl[ns] = *(const short8*)(kn + (size_t)(ns * 16) * DHh);
        kfh[ns] = *(const short8*)(kn + (size_t)(ns * 16) * DHh + 32);
      }
    }
    // ---- weights: p = exp2(s') / (1 + gm*delta); s' pre-scaled by log2e ----
    bool last = (kt == ktm);
    short8 pfrag[2][2];
#pragma unroll
    for (int qb = 0; qb < 2; ++qb) {
      int qrow = qb ? qrow1 : qrow0;
      float gm = qb ? gm1 : gm0;
      int db = qrow - kbase - g * 4;     // delta = db - ns*16 - r
      float fd = (float)db;
      float base = fmaf(gm, fd, 1.0f);
      float rsub[4] = {0.0f, 0.0f, 0.0f, 0.0f};
      if (last) {
#pragma unroll
        for (int e = 0; e < 16; ++e) {
          int off = (e >> 2) * 16 + (e & 3);
          if (db - off < 0) sv[qb][e] = -1e30f;
          float delta = fmaxf(fd - (float)off, 0.0f);
          float wt = __builtin_amdgcn_rcpf(fmaf(gm, delta, 1.0f));
          float pv = __builtin_amdgcn_exp2f(sv[qb][e]) * wt;
          rsub[e & 3] += pv;
          sv[qb][e] = pv;
        }
      } else {
        // non-diagonal tile: qrow >= u*64 > any key here -> delta >= 1
#pragma unroll
        for (int e = 0; e < 16; ++e) {
          float off = (float)((e >> 2) * 16 + (e & 3));
          float wt = __builtin_amdgcn_rcpf(fmaf(gm, -off, base));
          float pv = __builtin_amdgcn_exp2f(sv[qb][e]) * wt;
          rsub[e & 3] += pv;
          sv[qb][e] = pv;
        }
      }
      l2[qb] += (rsub[0] + rsub[1]) + (rsub[2] + rsub[3]);
#pragma unroll
      for (int cc = 0; cc < 2; ++cc) {
        uint4 pkd;
        pkd.x = packhi(sv[qb][8 * cc + 0], sv[qb][8 * cc + 1]);
        pkd.y = packhi(sv[qb][8 * cc + 2], sv[qb][8 * cc + 3]);
        pkd.z = packhi(sv[qb][8 * cc + 4], sv[qb][8 * cc + 5]);
        pkd.w = packhi(sv[qb][8 * cc + 6], sv[qb][8 * cc + 7]);
        pfrag[qb][cc] = *(short8*)&pkd;
      }
    }
    // ---- PV: O^T += V^T . P^T : 16 MFMAs ----
#pragma unroll
    for (int cc = 0; cc < 2; ++cc)
#pragma unroll
      for (int ds = 0; ds < 4; ++ds) {
        oacc[0][ds] = __builtin_amdgcn_mfma_f32_16x16x32_bf16(vf[cc * 4 + ds], pfrag[0][cc], oacc[0][ds], 0, 0, 0);
        oacc[1][ds] = __builtin_amdgcn_mfma_f32_16x16x32_bf16(vf[cc * 4 + ds], pfrag[1][cc], oacc[1][ds], 0, 0, 0);
      }
    // ---- prefetch next V tile ----
    if (kt + 1 < hi) {
#pragma unroll
      for (int cc = 0; cc < 8; ++cc)
        vf[cc] = *(const short8*)(vp + (size_t)((cc & 3) * 16) * Ss + kbase + 64 + (cc >> 2) * 32);
    }
  }

  // ---- merge halves (plain add), normalize, store ----
  if (half) {
#pragma unroll
    for (int qb = 0; qb < 2; ++qb)
#pragma unroll
      for (int ds = 0; ds < 4; ++ds)
#pragma unroll
        for (int r = 0; r < 4; ++r)
          Pmrg[qsel][lane][qb * 16 + ds * 4 + r] = oacc[qb][ds][r];
    Pmrg[qsel][lane][32] = l2[0];
    Pmrg[qsel][lane][33] = l2[1];
  }
  __syncthreads();
  if (!half) {
#pragma unroll
    for (int qb = 0; qb < 2; ++qb) {
#pragma unroll
      for (int ds = 0; ds < 4; ++ds)
#pragma unroll
        for (int r = 0; r < 4; ++r)
          oacc[qb][ds][r] += Pmrg[qsel][lane][qb * 16 + ds * 4 + r];
      float l = l2[qb] + Pmrg[qsel][lane][32 + qb];
      l += __shfl_xor(l, 16);
      l += __shfl_xor(l, 32);
      float linv = 1.0f / l;
      ushort* tb = &Tb[qsel][0];
#pragma unroll
      for (int ds = 0; ds < 4; ++ds)
#pragma unroll
        for (int r = 0; r < 4; ++r)
          tb[ln * 72 + ds * 16 + g * 4 + r] = bfbits(oacc[qb][ds][r] * linv);
      short8 v0 = *(const short8*)(tb + ln * 72 + g * 16);
      short8 v1 = *(const short8*)(tb + ln * 72 + g * 16 + 8);
      size_t oa = ((size_t)b * Ss + q0 + qb * 16 + ln) * Dd + hh * DHh + g * 16;
      *(short8*)(o + oa) = v0;
      *(short8*)(o + oa + 8) = v1;
    }
  }
}

extern "C" void kernel_launch(void* const* d_in, const int* in_sizes, int n_in,
                              void* d_out, int out_size, void* d_ws, size_t ws_size,
                              hipStream_t stream) {
  const float* x     = (const float*)d_in[0];
  const float* gamma = (const float*)d_in[1];
  const float* Wq    = (const float*)d_in[2];
  const float* bq    = (const float*)d_in[3];
  const float* Wk    = (const float*)d_in[4];
  const float* bk    = (const float*)d_in[5];
  const float* Wv    = (const float*)d_in[6];
  const float* bv    = (const float*)d_in[7];
  const float* Wo    = (const float*)d_in[8];
  const float* bo    = (const float*)d_in[9];

  const size_t NX = (size_t)Bb * Ss * Dd;
  const size_t NW = (size_t)Dd * Dd;
  ushort* xb  = (ushort*)d_ws;
  ushort* Wqb = xb + NX;
  ushort* Wkb = Wqb + NW;
  ushort* Wvb = Wkb + NW;
  ushort* Wob = Wvb + NW;
  ushort* qb  = Wob + NW;
  ushort* kb  = qb + NX;
  ushort* vtb = kb + NX;
  ushort* ab  = vtb + NX;

  const int total4 = (int)(NX / 4 + 4 * (NW / 4));
  cvt_all<<<(total4 + 255) / 256, 256, 0, stream>>>(x, Wq, Wk, Wv, Wo, xb);

  qkv_gemm<<<64 * 12, 256, 0, stream>>>(xb, Wqb, Wkb, Wvb, bq, bk, bv, qb, kb, vtb);

  flash11<<<1024, 256, 0, stream>>>(qb, kb, vtb, gamma, ab);

  gemm_out<<<512, 256, 0, stream>>>(ab, Wob, bo, (float*)d_out);
}

// Round 7
// 286.937 us; speedup vs baseline: 1.2297x; 1.2297x over previous
//
#include <hip/hip_runtime.h>
#include <hip/hip_bf16.h>

#define Bb 2
#define Ss 4096
#define Dd 512
#define Hh 8
#define DHh 64

typedef __attribute__((ext_vector_type(8))) short short8;
typedef __attribute__((ext_vector_type(4))) float floatx4;

static __device__ __forceinline__ ushort bfbits(float f) {
  union { __hip_bfloat16 h; ushort u; } cv;
  cv.h = __float2bfloat16(f);
  return cv.u;
}

// pack two fp32 -> two bf16 (truncation; P-weights only, 2^-8 rel err)
static __device__ __forceinline__ unsigned int packhi(float a, float b) {
  union { float f; unsigned int u; } ca, cb; ca.f = a; cb.f = b;
  return (ca.u >> 16) | (cb.u & 0xffff0000u);
}

// ---------------- merged fp32 -> bf16: [x | Wq | Wk | Wv | Wo] ----------------
__global__ void cvt_all(const float* __restrict__ x,
                        const float* __restrict__ w0, const float* __restrict__ w1,
                        const float* __restrict__ w2, const float* __restrict__ w3,
                        ushort* __restrict__ out) {
  const int XN4 = (Bb * Ss * Dd) / 4;
  const int WN4 = (Dd * Dd) / 4;        // 65,536 = 2^16
  int i = blockIdx.x * blockDim.x + threadIdx.x;
  if (i >= XN4 + 4 * WN4) return;
  const float* s; int li;
  if (i < XN4) { s = x; li = i; }
  else {
    int t = i - XN4; int j = t >> 16; li = t & (WN4 - 1);
    s = (j == 0) ? w0 : (j == 1) ? w1 : (j == 2) ? w2 : w3;
  }
  float4 f = ((const float4*)s)[li];
  ushort4 u;
  u.x = bfbits(f.x); u.y = bfbits(f.y); u.z = bfbits(f.z); u.w = bfbits(f.w);
  ((ushort4*)out)[i] = u;
}

// permuted V^T position: key s -> within-64 slot so flash PV A-frags are
// single contiguous 16B loads.
static __device__ __forceinline__ int vperm(int s0) {  // s0 multiple of 4
  int kb = (s0 >> 4) & 3, gq = (s0 >> 2) & 3;
  return (s0 & ~63) | ((kb >> 1) << 5) | (gq << 3) | ((kb & 1) << 2);
}

// ---------------- fused QKV projection GEMM ----------------
// Wave computes 64x64 (4x4 MFMA tiles): 8 loads per 16 MFMAs per K-step-32.
// Block = 4 waves (2x2) = 128x128 tile. Grid 64 mb x 12 (which x nb) = 768.
#define LDQK(buf, k0)                                                          \
  _Pragma("unroll")                                                            \
  for (int rb = 0; rb < 4; ++rb)                                               \
    af[buf][rb] = *(const short8*)(ap + (size_t)rb * 16 * 512 + (k0));         \
  _Pragma("unroll")                                                            \
  for (int cb = 0; cb < 4; ++cb)                                               \
    bf[buf][cb] = *(const short8*)(bp + (size_t)cb * 16 * 512 + (k0));

__global__ __launch_bounds__(256) void qkv_gemm(
    const ushort* __restrict__ xb,
    const ushort* __restrict__ Wq, const ushort* __restrict__ Wk, const ushort* __restrict__ Wv,
    const float* __restrict__ bq, const float* __restrict__ bk, const float* __restrict__ bv,
    ushort* __restrict__ qo, ushort* __restrict__ ko, ushort* __restrict__ vo)
{
  int mb = blockIdx.x / 12, rest = blockIdx.x % 12;
  int which = rest >> 2, nb = rest & 3;
  const ushort* Bw  = (which == 0) ? Wq : (which == 1) ? Wk : Wv;
  const float* bias = (which == 0) ? bq : (which == 1) ? bk : bv;
  int lane = threadIdx.x & 63, w = threadIdx.x >> 6;
  int wr = w & 1, wc = w >> 1;
  int g = lane >> 4, ln = lane & 15;
  int m0 = mb * 128 + wr * 64;
  int c0 = nb * 128 + wc * 64;
  const ushort* ap = xb + (size_t)(m0 + ln) * 512 + g * 8;
  const ushort* bp = Bw + (size_t)(c0 + ln) * 512 + g * 8;
  floatx4 acc[4][4] = {};
  short8 af[2][4], bf[2][4];
  LDQK(0, 0)
#pragma unroll
  for (int it = 0; it < 16; ++it) {
    int cur = it & 1;
    if (it < 15) { LDQK(cur ^ 1, (it + 1) * 32) }
#pragma unroll
    for (int rb = 0; rb < 4; ++rb)
#pragma unroll
      for (int cb = 0; cb < 4; ++cb)
        acc[rb][cb] = __builtin_amdgcn_mfma_f32_16x16x32_bf16(af[cur][rb], bf[cur][cb], acc[rb][cb], 0, 0, 0);
  }
  // Q scale = (1/8) * log2(e): softmax then uses raw exp2 (v_exp_f32),
  // saving one v_mul per score element in the flash kernel.
  float scale = (which == 0) ? 0.18033688011112042f : 1.0f;
#pragma unroll
  for (int rb = 0; rb < 4; ++rb)
#pragma unroll
    for (int cb = 0; cb < 4; ++cb) {
      int col = c0 + cb * 16 + ln;
      float bv_ = bias[col];
      int hh = col >> 6, dh = col & 63;
      if (which == 2) {
        int i0 = m0 + rb * 16 + g * 4;
        int bI = i0 >> 12, s0 = i0 & (Ss - 1);
        ushort4 pk;
        pk.x = bfbits(acc[rb][cb][0] + bv_);
        pk.y = bfbits(acc[rb][cb][1] + bv_);
        pk.z = bfbits(acc[rb][cb][2] + bv_);
        pk.w = bfbits(acc[rb][cb][3] + bv_);
        *(ushort4*)(vo + (((size_t)bI * Hh + hh) * DHh + dh) * Ss + vperm(s0)) = pk;
      } else {
        ushort* outp = (which == 0) ? qo : ko;
#pragma unroll
        for (int r = 0; r < 4; ++r) {
          int i = m0 + rb * 16 + g * 4 + r;
          int bI = i >> 12, s = i & (Ss - 1);
          outp[(((size_t)bI * Hh + hh) * Ss + s) * DHh + dh] = bfbits((acc[rb][cb][r] + bv_) * scale);
        }
      }
    }
}

// ---------------- output projection GEMM (fp32 out) ----------------
#define LD32(buf, k0)                                                          \
  af[buf][0] = *(const short8*)(ap + (k0));                                    \
  af[buf][1] = *(const short8*)(ap + 16 * 512 + (k0));                         \
  _Pragma("unroll")                                                            \
  for (int ns = 0; ns < 4; ++ns)                                               \
    bfr[buf][ns] = *(const short8*)(bp + (size_t)ns * 16 * 512 + (k0));

__global__ __launch_bounds__(256) void gemm_out(
    const ushort* __restrict__ A, const ushort* __restrict__ Bw,
    const float* __restrict__ bias, float* __restrict__ outp)
{
  int mb = blockIdx.x >> 3, nb = blockIdx.x & 7;
  int lane = threadIdx.x & 63, w = threadIdx.x >> 6;
  int g = lane >> 4, ln = lane & 15;
  int m0 = mb * 128 + w * 32;
  const ushort* ap = A + (size_t)(m0 + ln) * 512 + g * 8;
  const ushort* bp = Bw + (size_t)(nb * 64 + ln) * 512 + g * 8;
  floatx4 acc[2][4] = {};
  short8 af[2][2], bfr[2][4];
  LD32(0, 0)
#pragma unroll
  for (int it = 0; it < 16; ++it) {
    int cur = it & 1;
    if (it < 15) { LD32(cur ^ 1, (it + 1) * 32) }
#pragma unroll
    for (int ns = 0; ns < 4; ++ns) {
      acc[0][ns] = __builtin_amdgcn_mfma_f32_16x16x32_bf16(af[cur][0], bfr[cur][ns], acc[0][ns], 0, 0, 0);
      acc[1][ns] = __builtin_amdgcn_mfma_f32_16x16x32_bf16(af[cur][1], bfr[cur][ns], acc[1][ns], 0, 0, 0);
    }
  }
#pragma unroll
  for (int rb = 0; rb < 2; ++rb)
#pragma unroll
    for (int ns = 0; ns < 4; ++ns) {
      int col = nb * 64 + ns * 16 + ln;
      float bv_ = bias[col];
#pragma unroll
      for (int r = 0; r < 4; ++r)
        outp[(size_t)(m0 + rb * 16 + g * 4 + r) * 512 + col] = acc[rb][ns][r] + bv_;
    }
}

// ---------------- flash attention v12 ----------------
// Register model (fits rounds 0-6): wave footprint = arch VGPR + ~64 acc.
// v6/v8/v9/v10 at 104-128 arch -> 2 waves/SIMD; v11's forced cap -> spills.
// v12 targets 3 waves/SIMD with BOTH: (a) supply 12 waves/CU -- 1024 blocks
// x 192 thr (3 waves) = (bh, qsel, up), rep-paired u=up then 63-up; per rep
// the 3 waves split that task's tiles 3-ways; per-wave total = 65/3 uniform
// -> exactly 4 blocks/CU resident, zero drain; (b) live-set shave: softmax
// at (qb, ns-pair) granularity (4 MFMAs -> 8 scores -> weights -> 4-reg
// pfrag piece; sv peak 32->8) and V loaded per 32-key half inside PV
// (vf 32->16). Slot-based LDS merge (no atomics), wave0 finalizes.
// No launch-bounds min (v7/v11 lesson: never force below the live set).
__global__ __launch_bounds__(192) void flash12(
    const ushort* __restrict__ q, const ushort* __restrict__ k,
    const ushort* __restrict__ vt, const float* __restrict__ gamma,
    ushort* __restrict__ o)
{
  __shared__ __align__(16) float Pmrg[2][64][34];   // slots for waves 1,2
  __shared__ __align__(16) ushort Tb[16 * 72];      // store-transpose staging

  int z = blockIdx.x;
  int bh = z & 15;                 // XCD x serves bh {x, x+8}: K/V L2-resident
  int b = bh >> 3, hh = bh & 7;
  int qsel = (z >> 4) & 1;
  int up = z >> 5;                 // 0..31

  int tid = threadIdx.x;
  int wv = tid >> 6, lane = tid & 63;   // wv in 0..2
  int g = lane >> 4, ln = lane & 15;

  const ushort* kp = k + ((size_t)bh * Ss + ln) * DHh + g * 8;
  const ushort* vp = vt + ((size_t)bh * DHh + ln) * Ss + g * 8;

#pragma unroll 1
  for (int rep = 0; rep < 2; ++rep) {
    int u = rep ? (63 - up) : up;
    int nkt = u + 1;
    int ktm = u;                   // diagonal (masked) tile
    int qd = nkt / 3, rr = nkt % 3;
    int lo = wv * qd + (wv < rr ? wv : rr);
    int hi = lo + qd + (wv < rr ? 1 : 0);
    int q0 = (2 * u + qsel) * 32;

    const ushort* qp = q + ((size_t)bh * Ss + q0 + ln) * DHh + g * 8;
    short8 qf00 = *(const short8*)qp;
    short8 qf01 = *(const short8*)(qp + 32);
    short8 qf10 = *(const short8*)(qp + 16 * DHh);
    short8 qf11 = *(const short8*)(qp + 16 * DHh + 32);

    int qrow0 = q0 + ln, qrow1 = q0 + 16 + ln;
    float gm0 = gamma[(size_t)b * Ss + qrow0];
    float gm1 = gamma[(size_t)b * Ss + qrow1];
    float l2[2] = {0.0f, 0.0f};
    floatx4 oacc[2][4] = {};

    if (lo < hi) {
      short8 kfl[4], kfh[4];
      int kb0 = lo * 64;
#pragma unroll
      for (int ns = 0; ns < 4; ++ns) {
        kfl[ns] = *(const short8*)(kp + (size_t)(kb0 + ns * 16) * DHh);
        kfh[ns] = *(const short8*)(kp + (size_t)(kb0 + ns * 16) * DHh + 32);
      }

      for (int kt = lo; kt < hi; ++kt) {
        int kbase = kt * 64;
        bool last = (kt == ktm);
        short8 pfrag[2][2];
        // ---- fine-grained QK^T + softmax: per (qb, ns-pair) ----
#pragma unroll
        for (int qb = 0; qb < 2; ++qb) {
          short8 qlo = qb ? qf10 : qf00;
          short8 qhi = qb ? qf11 : qf01;
          int qrow = qb ? qrow1 : qrow0;
          float gm = qb ? gm1 : gm0;
          int db = qrow - kbase - g * 4;   // delta = db - (ns*16 + r)
          float fd = (float)db;
          float base = fmaf(gm, fd, 1.0f);
#pragma unroll
          for (int nsg = 0; nsg < 2; ++nsg) {
            floatx4 za = {}, zb = {};
            za = __builtin_amdgcn_mfma_f32_16x16x32_bf16(kfl[2 * nsg + 0], qlo, za, 0, 0, 0);
            za = __builtin_amdgcn_mfma_f32_16x16x32_bf16(kfh[2 * nsg + 0], qhi, za, 0, 0, 0);
            zb = __builtin_amdgcn_mfma_f32_16x16x32_bf16(kfl[2 * nsg + 1], qlo, zb, 0, 0, 0);
            zb = __builtin_amdgcn_mfma_f32_16x16x32_bf16(kfh[2 * nsg + 1], qhi, zb, 0, 0, 0);
            float f[8];
#pragma unroll
            for (int r = 0; r < 4; ++r) { f[r] = za[r]; f[4 + r] = zb[r]; }
            float rs0 = 0.0f, rs1 = 0.0f;
            if (last) {
#pragma unroll
              for (int e = 0; e < 8; ++e) {
                int off = nsg * 32 + (e >> 2) * 16 + (e & 3);
                if (db - off < 0) f[e] = -1e30f;
                float delta = fmaxf(fd - (float)off, 0.0f);
                float wt = __builtin_amdgcn_rcpf(fmaf(gm, delta, 1.0f));
                float pv = __builtin_amdgcn_exp2f(f[e]) * wt;
                if (e & 1) rs1 += pv; else rs0 += pv;
                f[e] = pv;
              }
            } else {
              // non-diagonal tile: qrow >= u*64 > any key here -> delta >= 1
#pragma unroll
              for (int e = 0; e < 8; ++e) {
                float off = (float)(nsg * 32 + (e >> 2) * 16 + (e & 3));
                float wt = __builtin_amdgcn_rcpf(fmaf(gm, -off, base));
                float pv = __builtin_amdgcn_exp2f(f[e]) * wt;
                if (e & 1) rs1 += pv; else rs0 += pv;
                f[e] = pv;
              }
            }
            l2[qb] += rs0 + rs1;
            uint4 pkd;
            pkd.x = packhi(f[0], f[1]);
            pkd.y = packhi(f[2], f[3]);
            pkd.z = packhi(f[4], f[5]);
            pkd.w = packhi(f[6], f[7]);
            pfrag[qb][nsg] = *(short8*)&pkd;
          }
        }
        // ---- prefetch next K tile ----
        if (kt + 1 < hi) {
          const ushort* kn = kp + (size_t)(kbase + 64) * DHh;
#pragma unroll
          for (int ns = 0; ns < 4; ++ns) {
            kfl[ns] = *(const short8*)(kn + (size_t)(ns * 16) * DHh);
            kfh[ns] = *(const short8*)(kn + (size_t)(ns * 16) * DHh + 32);
          }
        }
        // ---- PV per 32-key half: load 4 V frags, 8 MFMAs ----
#pragma unroll
        for (int c = 0; c < 2; ++c) {
          short8 vfg[4];
#pragma unroll
          for (int ds = 0; ds < 4; ++ds)
            vfg[ds] = *(const short8*)(vp + (size_t)(ds * 16) * Ss + kbase + c * 32);
#pragma unroll
          for (int ds = 0; ds < 4; ++ds) {
            oacc[0][ds] = __builtin_amdgcn_mfma_f32_16x16x32_bf16(vfg[ds], pfrag[0][c], oacc[0][ds], 0, 0, 0);
            oacc[1][ds] = __builtin_amdgcn_mfma_f32_16x16x32_bf16(vfg[ds], pfrag[1][c], oacc[1][ds], 0, 0, 0);
          }
        }
      }
    }

    // ---- slot merge: waves 1,2 write; wave 0 adds, normalizes, stores ----
    if (wv) {
#pragma unroll
      for (int qb = 0; qb < 2; ++qb)
#pragma unroll
        for (int ds = 0; ds < 4; ++ds)
#pragma unroll
          for (int r = 0; r < 4; ++r)
            Pmrg[wv - 1][lane][qb * 16 + ds * 4 + r] = oacc[qb][ds][r];
      Pmrg[wv - 1][lane][32] = l2[0];
      Pmrg[wv - 1][lane][33] = l2[1];
    }
    __syncthreads();
    if (wv == 0) {
#pragma unroll
      for (int qb = 0; qb < 2; ++qb) {
#pragma unroll
        for (int ds = 0; ds < 4; ++ds)
#pragma unroll
          for (int r = 0; r < 4; ++r)
            oacc[qb][ds][r] += Pmrg[0][lane][qb * 16 + ds * 4 + r]
                             + Pmrg[1][lane][qb * 16 + ds * 4 + r];
        float l = l2[qb] + Pmrg[0][lane][32 + qb] + Pmrg[1][lane][32 + qb];
        l += __shfl_xor(l, 16);
        l += __shfl_xor(l, 32);
        float linv = 1.0f / l;
        ushort* tb = &Tb[0];
#pragma unroll
        for (int ds = 0; ds < 4; ++ds)
#pragma unroll
          for (int r = 0; r < 4; ++r)
            tb[ln * 72 + ds * 16 + g * 4 + r] = bfbits(oacc[qb][ds][r] * linv);
        short8 v0 = *(const short8*)(tb + ln * 72 + g * 16);
        short8 v1 = *(const short8*)(tb + ln * 72 + g * 16 + 8);
        size_t oa = ((size_t)b * Ss + q0 + qb * 16 + ln) * Dd + hh * DHh + g * 16;
        *(short8*)(o + oa) = v0;
        *(short8*)(o + oa + 8) = v1;
      }
    }
    __syncthreads();                // guard Pmrg/Tb reuse across reps
  }
}

extern "C" void kernel_launch(void* const* d_in, const int* in_sizes, int n_in,
                              void* d_out, int out_size, void* d_ws, size_t ws_size,
                              hipStream_t stream) {
  const float* x     = (const float*)d_in[0];
  const float* gamma = (const float*)d_in[1];
  const float* Wq    = (const float*)d_in[2];
  const float* bq    = (const float*)d_in[3];
  const float* Wk    = (const float*)d_in[4];
  const float* bk    = (const float*)d_in[5];
  const float* Wv    = (const float*)d_in[6];
  const float* bv    = (const float*)d_in[7];
  const float* Wo    = (const float*)d_in[8];
  const float* bo    = (const float*)d_in[9];

  const size_t NX = (size_t)Bb * Ss * Dd;
  const size_t NW = (size_t)Dd * Dd;
  ushort* xb  = (ushort*)d_ws;
  ushort* Wqb = xb + NX;
  ushort* Wkb = Wqb + NW;
  ushort* Wvb = Wkb + NW;
  ushort* Wob = Wvb + NW;
  ushort* qb  = Wob + NW;
  ushort* kb  = qb + NX;
  ushort* vtb = kb + NX;
  ushort* ab  = vtb + NX;

  const int total4 = (int)(NX / 4 + 4 * (NW / 4));
  cvt_all<<<(total4 + 255) / 256, 256, 0, stream>>>(x, Wq, Wk, Wv, Wo, xb);

  qkv_gemm<<<64 * 12, 256, 0, stream>>>(xb, Wqb, Wkb, Wvb, bq, bk, bv, qb, kb, vtb);

  flash12<<<1024, 192, 0, stream>>>(qb, kb, vtb, gamma, ab);

  gemm_out<<<512, 256, 0, stream>>>(ab, Wob, bo, (float*)d_out);
}